// Round 4
// baseline (494.717 us; speedup 1.0000x reference)
//
#include <hip/hip_runtime.h>

#define TOKENS 2048
#define HIDDEN 2048
#define INTER  768
#define NEXP   16
#define NA     (TOKENS * 2)
#define MTILE  128
#define MAXT   64

typedef unsigned int   uint32;
typedef unsigned short u16;
typedef __bf16 bf16x8 __attribute__((ext_vector_type(8)));
typedef float  f32x4  __attribute__((ext_vector_type(4)));

__device__ __forceinline__ u16 f2bf(float f) {
    union { float f; uint32 u; } v; v.f = f;
    return (u16)((v.u + 0x7fffu + ((v.u >> 16) & 1u)) >> 16);
}
// fast pack of two fp32 -> two bf16 (round-half-away; fine vs 2% threshold)
__device__ __forceinline__ uint32 pk2(float a, float b) {
    union { float f; uint32 u; } x, y; x.f = a; y.f = b;
    return ((x.u + 0x8000u) >> 16) | ((y.u + 0x8000u) & 0xffff0000u);
}
__device__ __forceinline__ uint4 cvt8f(float4 a, float4 b) {
    uint4 o;
    o.x = pk2(a.x, a.y); o.y = pk2(a.z, a.w);
    o.z = pk2(b.x, b.y); o.w = pk2(b.z, b.w);
    return o;
}
// 16B-unit index into a rowstride-64 bf16 LDS tile, XOR-swizzled
__device__ __forceinline__ int swz(int row, int k8) { return row * 8 + (k8 ^ (row & 7)); }

// ---------------- X: fp32 -> bf16 once ----------------
__global__ void xcvt_kernel(const float* __restrict__ X, u16* __restrict__ Xb) {
    const int gid = blockIdx.x * 256 + threadIdx.x;
    const float4* s = (const float4*)X + (size_t)gid * 2;
    ((uint4*)Xb)[gid] = cvt8f(s[0], s[1]);
}

// ---------------- routing: bucket assignments, emit m-tile list ----------------
__global__ void route_kernel(const int* __restrict__ idx, int* __restrict__ meta,
                             int* __restrict__ bucket) {
    __shared__ int scnt[NEXP];
    __shared__ int soff[NEXP + 1];
    __shared__ int sfill[NEXP];
    __shared__ int sflag;
    const int tid = threadIdx.x;
    if (tid < NEXP) { scnt[tid] = 0; sfill[tid] = 0; }
    if (tid == 0) sflag = 0;
    __syncthreads();
    int any = 0;   // int64 buffers have all-zero odd words
    for (int a = tid; a < NA / 2; a += 256) any |= idx[2 * a + 1];
    if (any) atomicOr(&sflag, 1);
    __syncthreads();
    const int stride = sflag ? 1 : 2;
    for (int a = tid; a < NA; a += 256) atomicAdd(&scnt[idx[a * stride]], 1);
    __syncthreads();
    if (tid == 0) {
        int s = 0;
        for (int e = 0; e < NEXP; ++e) { soff[e] = s; s += scnt[e]; }
        soff[NEXP] = s;
        int nt = 0;
        for (int e = 0; e < NEXP; ++e) {
            const int ne = soff[e + 1] - soff[e];
            for (int m0 = 0; m0 < ne; m0 += MTILE) {
                meta[32 + nt] = e;
                meta[96 + nt] = m0;
                ++nt;
            }
        }
        meta[17] = nt;
    }
    __syncthreads();
    for (int a = tid; a < NA; a += 256) {
        int e = idx[a * stride];
        int slot = atomicAdd(&sfill[e], 1);
        bucket[soff[e] + slot] = a;
    }
    if (tid <= NEXP) meta[tid] = soff[tid];
}

// ---------------- GEMM1: gate/up + SwiGLU -> H (slot-ordered, bf16) ----------------
// 128 slots x 64 inter-cols per block; register-prefetch pipelined K-loop.
__global__ __launch_bounds__(256, 2) void gemm1_kernel(
    const u16* __restrict__ Xb,    // [TOKENS, HIDDEN] bf16
    const float* __restrict__ Wg,  // [NEXP, INTER, HIDDEN] fp32
    const float* __restrict__ Wu,  // [NEXP, INTER, HIDDEN] fp32
    const int* __restrict__ meta, const int* __restrict__ bucket,
    u16* __restrict__ Hbuf)        // [NA, INTER] bf16, slot-ordered
{
    const int ty = blockIdx.y;
    if (ty >= meta[17]) return;
    const int e    = meta[32 + ty];
    const int m0   = meta[96 + ty];
    const int j0   = blockIdx.x * 64;
    const int base = meta[e];
    const int ne   = meta[e + 1] - base;

    __shared__ u16 Xs[MTILE * 64];
    __shared__ u16 Gs[64 * 64];
    __shared__ u16 Us[64 * 64];

    const int tid  = threadIdx.x;
    const int lane = tid & 63;
    const int wm   = (tid >> 6) * 32;
    const int lr   = lane & 15;
    const int lq   = lane >> 4;
    const int srow = tid >> 3;    // staging row 0..31
    const int lc8  = tid & 7;     // staging 16B chunk

    const u16* xp[4];
#pragma unroll
    for (int p = 0; p < 4; ++p) {
        int slot = m0 + srow + p * 32;
        slot = slot < ne ? slot : ne - 1;
        xp[p] = Xb + (size_t)(bucket[base + slot] >> 1) * HIDDEN + lc8 * 8;
    }
    const float* gp0 = Wg + ((size_t)e * INTER + j0 + srow) * HIDDEN + lc8 * 8;
    const float* gp1 = gp0 + (size_t)32 * HIDDEN;
    const float* up0 = Wu + ((size_t)e * INTER + j0 + srow) * HIDDEN + lc8 * 8;
    const float* up1 = up0 + (size_t)32 * HIDDEN;

    uint4  px[4];
    float4 pg[4], pu[4];
#pragma unroll
    for (int p = 0; p < 4; ++p) px[p] = *(const uint4*)xp[p];
    pg[0] = ((const float4*)gp0)[0]; pg[1] = ((const float4*)gp0)[1];
    pg[2] = ((const float4*)gp1)[0]; pg[3] = ((const float4*)gp1)[1];
    pu[0] = ((const float4*)up0)[0]; pu[1] = ((const float4*)up0)[1];
    pu[2] = ((const float4*)up1)[0]; pu[3] = ((const float4*)up1)[1];

    f32x4 ag[2][4] = {};
    f32x4 au[2][4] = {};
    for (int k0 = 0; k0 < HIDDEN; k0 += 64) {
        __syncthreads();
#pragma unroll
        for (int p = 0; p < 4; ++p)
            *(uint4*)(Xs + swz(srow + p * 32, lc8) * 8) = px[p];
        *(uint4*)(Gs + swz(srow,      lc8) * 8) = cvt8f(pg[0], pg[1]);
        *(uint4*)(Gs + swz(srow + 32, lc8) * 8) = cvt8f(pg[2], pg[3]);
        *(uint4*)(Us + swz(srow,      lc8) * 8) = cvt8f(pu[0], pu[1]);
        *(uint4*)(Us + swz(srow + 32, lc8) * 8) = cvt8f(pu[2], pu[3]);
        __syncthreads();
        if (k0 + 64 < HIDDEN) {   // prefetch next k-tile; waited on at next store
#pragma unroll
            for (int p = 0; p < 4; ++p) { xp[p] += 64; px[p] = *(const uint4*)xp[p]; }
            gp0 += 64; gp1 += 64; up0 += 64; up1 += 64;
            pg[0] = ((const float4*)gp0)[0]; pg[1] = ((const float4*)gp0)[1];
            pg[2] = ((const float4*)gp1)[0]; pg[3] = ((const float4*)gp1)[1];
            pu[0] = ((const float4*)up0)[0]; pu[1] = ((const float4*)up0)[1];
            pu[2] = ((const float4*)up1)[0]; pu[3] = ((const float4*)up1)[1];
        }
#pragma unroll
        for (int kk = 0; kk < 2; ++kk) {
            const int k8 = kk * 4 + lq;
            bf16x8 af[2], bg[4], bu[4];
#pragma unroll
            for (int i = 0; i < 2; ++i)
                af[i] = *(const bf16x8*)(Xs + swz(wm + i * 16 + lr, k8) * 8);
#pragma unroll
            for (int j = 0; j < 4; ++j) {
                bg[j] = *(const bf16x8*)(Gs + swz(j * 16 + lr, k8) * 8);
                bu[j] = *(const bf16x8*)(Us + swz(j * 16 + lr, k8) * 8);
            }
#pragma unroll
            for (int i = 0; i < 2; ++i)
#pragma unroll
                for (int j = 0; j < 4; ++j) {
                    ag[i][j] = __builtin_amdgcn_mfma_f32_16x16x32_bf16(af[i], bg[j], ag[i][j], 0, 0, 0);
                    au[i][j] = __builtin_amdgcn_mfma_f32_16x16x32_bf16(af[i], bu[j], au[i][j], 0, 0, 0);
                }
        }
    }
    // epilogue: h = silu(g)*u ; C layout col=lane&15, row=lq*4+r
#pragma unroll
    for (int i = 0; i < 2; ++i)
#pragma unroll
        for (int r = 0; r < 4; ++r) {
            const int slot = m0 + wm + i * 16 + lq * 4 + r;
            if (slot < ne) {
#pragma unroll
                for (int j = 0; j < 4; ++j) {
                    const float g = ag[i][j][r];
                    const float u = au[i][j][r];
                    const float h = (g / (1.f + __expf(-g))) * u;
                    Hbuf[(size_t)(base + slot) * INTER + j0 + j * 16 + lr] = f2bf(h);
                }
            }
        }
}

// ---------------- GEMM2: down-proj -> weighted atomicAdd into out ----------------
__global__ __launch_bounds__(256, 2) void gemm2_kernel(
    const u16* __restrict__ Hbuf,   // [NA, INTER] bf16, slot-ordered
    const float* __restrict__ Wd,   // [NEXP, HIDDEN, INTER] fp32
    const float* __restrict__ tkw,  // [TOKENS, 2] fp32
    const int* __restrict__ meta, const int* __restrict__ bucket,
    float* __restrict__ out)        // [TOKENS, HIDDEN] fp32, pre-zeroed
{
    const int ty = blockIdx.y;
    if (ty >= meta[17]) return;
    const int e    = meta[32 + ty];
    const int m0   = meta[96 + ty];
    const int n0   = blockIdx.x * 64;
    const int base = meta[e];
    const int ne   = meta[e + 1] - base;

    __shared__ u16 Hs[MTILE * 64];
    __shared__ u16 Ds[64 * 64];

    const int tid  = threadIdx.x;
    const int lane = tid & 63;
    const int wm   = (tid >> 6) * 32;
    const int lr   = lane & 15;
    const int lq   = lane >> 4;
    const int srow = tid >> 3;
    const int lc8  = tid & 7;

    const u16* hp[4];
#pragma unroll
    for (int p = 0; p < 4; ++p) {
        int slot = m0 + srow + p * 32;
        slot = slot < ne ? slot : ne - 1;
        hp[p] = Hbuf + (size_t)(base + slot) * INTER + lc8 * 8;
    }
    const float* dp0 = Wd + ((size_t)e * HIDDEN + n0 + srow) * INTER + lc8 * 8;
    const float* dp1 = dp0 + (size_t)32 * INTER;

    uint4  ph[4];
    float4 pd[4];
#pragma unroll
    for (int p = 0; p < 4; ++p) ph[p] = *(const uint4*)hp[p];
    pd[0] = ((const float4*)dp0)[0]; pd[1] = ((const float4*)dp0)[1];
    pd[2] = ((const float4*)dp1)[0]; pd[3] = ((const float4*)dp1)[1];

    f32x4 ac[2][4] = {};
    for (int k0 = 0; k0 < INTER; k0 += 64) {
        __syncthreads();
#pragma unroll
        for (int p = 0; p < 4; ++p)
            *(uint4*)(Hs + swz(srow + p * 32, lc8) * 8) = ph[p];
        *(uint4*)(Ds + swz(srow,      lc8) * 8) = cvt8f(pd[0], pd[1]);
        *(uint4*)(Ds + swz(srow + 32, lc8) * 8) = cvt8f(pd[2], pd[3]);
        __syncthreads();
        if (k0 + 64 < INTER) {
#pragma unroll
            for (int p = 0; p < 4; ++p) { hp[p] += 64; ph[p] = *(const uint4*)hp[p]; }
            dp0 += 64; dp1 += 64;
            pd[0] = ((const float4*)dp0)[0]; pd[1] = ((const float4*)dp0)[1];
            pd[2] = ((const float4*)dp1)[0]; pd[3] = ((const float4*)dp1)[1];
        }
#pragma unroll
        for (int kk = 0; kk < 2; ++kk) {
            const int k8 = kk * 4 + lq;
            bf16x8 af[2], bd[4];
#pragma unroll
            for (int i = 0; i < 2; ++i)
                af[i] = *(const bf16x8*)(Hs + swz(wm + i * 16 + lr, k8) * 8);
#pragma unroll
            for (int j = 0; j < 4; ++j)
                bd[j] = *(const bf16x8*)(Ds + swz(j * 16 + lr, k8) * 8);
#pragma unroll
            for (int i = 0; i < 2; ++i)
#pragma unroll
                for (int j = 0; j < 4; ++j)
                    ac[i][j] = __builtin_amdgcn_mfma_f32_16x16x32_bf16(af[i], bd[j], ac[i][j], 0, 0, 0);
        }
    }
#pragma unroll
    for (int i = 0; i < 2; ++i)
#pragma unroll
        for (int r = 0; r < 4; ++r) {
            const int slot = m0 + wm + i * 16 + lq * 4 + r;
            if (slot < ne) {
                const int a = bucket[base + slot];
                const int t = a >> 1;
                const float w = tkw[a];
#pragma unroll
                for (int j = 0; j < 4; ++j)
                    atomicAdd(out + (size_t)t * HIDDEN + n0 + j * 16 + lr, w * ac[i][j][r]);
            }
        }
}

extern "C" void kernel_launch(void* const* d_in, const int* in_sizes, int n_in,
                              void* d_out, int out_size, void* d_ws, size_t ws_size,
                              hipStream_t stream) {
    const float* X   = (const float*)d_in[0];
    const int*   idx = (const int*)d_in[1];
    const float* tkw = (const float*)d_in[2];
    const float* Wg  = (const float*)d_in[3];
    const float* Wu  = (const float*)d_in[4];
    const float* Wd  = (const float*)d_in[5];
    float* out = (float*)d_out;

    char* ws = (char*)d_ws;
    int* meta   = (int*)ws;                     // off[0..16], ntiles[17], tileE[32..], tileM0[96..]
    int* bucket = (int*)(ws + 1024);
    u16* Xb     = (u16*)(ws + 32768);
    u16* Hbuf   = (u16*)(ws + 32768 + (size_t)TOKENS * HIDDEN * 2);

    hipMemsetAsync(out, 0, (size_t)TOKENS * HIDDEN * sizeof(float), stream);
    xcvt_kernel<<<TOKENS * HIDDEN / 8 / 256, 256, 0, stream>>>(X, Xb);
    route_kernel<<<1, 256, 0, stream>>>(idx, meta, bucket);
    dim3 g1(INTER / 64, MAXT);
    gemm1_kernel<<<g1, 256, 0, stream>>>(Xb, Wg, Wu, meta, bucket, Hbuf);
    dim3 g2(HIDDEN / 64, MAXT);
    gemm2_kernel<<<g2, 256, 0, stream>>>(Hbuf, Wd, tkw, meta, bucket, out);
}